// Round 25
// baseline (745.186 us; speedup 1.0000x reference)
//
#include <hip/hip_runtime.h>
#include <math.h>

#define NB 16
#define NC 256
#define NP 4096      // 64*64
#define NHEADS 8
#define NDH 32
#define NBH 128
#define NFF 1024
#define CEPS 1e-5f

typedef short s16x8 __attribute__((ext_vector_type(8)));
typedef float f32x4 __attribute__((ext_vector_type(4)));

// ---------------- diagnostic fill (guard trip) ----------------
__global__ __launch_bounds__(256) void diag_fill(float* __restrict__ out, float val, int n)
{
    int i = blockIdx.x * 256 + threadIdx.x;
    if (i < n) out[i] = val;
}

// ---------------- bf16 split helpers ----------------
__device__ inline unsigned short f2bf(float f) {
    unsigned u = __float_as_uint(f);
    return (unsigned short)((u + 0x7FFFu + ((u >> 16) & 1u)) >> 16);
}
__device__ inline float bf2f(unsigned short h) { return __uint_as_float(((unsigned)h) << 16); }
__device__ inline void split2(float f, unsigned short& hi, unsigned short& lo) {
    hi = f2bf(f);
    lo = f2bf(f - bf2f(hi));
}
// fast round-to-nearest split (6 ops)
__device__ inline void split_rn(float f, unsigned short& hi, unsigned short& lo) {
    unsigned u = __float_as_uint(f);
    unsigned tt = u + 0x8000u;
    hi = (unsigned short)(tt >> 16);
    float r = f - __uint_as_float(tt & 0xffff0000u);
    lo = (unsigned short)((__float_as_uint(r) + 0x8000u) >> 16);
}
// packed: (hi<<16)|lo
__device__ inline unsigned pack_hl(float f) {
    unsigned short h, lo; split2(f, h, lo);
    return ((unsigned)h << 16) | (unsigned)lo;
}
__device__ inline float packf(float f) { return __uint_as_float(pack_hl(f)); }

// ---------------- weight prepack with channel gain: pw = pack(w[o,c]*g[c]) ----------
__global__ __launch_bounds__(256) void pack_wg_kernel(
    const float* __restrict__ w, const float* __restrict__ g,
    unsigned* __restrict__ pw, int n)
{
    int i = blockIdx.x * 256 + threadIdx.x;
    if (i < n) pw[i] = pack_hl(w[i] * g[i & 255]);
}

// ---------------- plain weight prepack: pw = pack(w[i]) ----------
__global__ __launch_bounds__(256) void pack_w_plain_kernel(
    const float* __restrict__ w, unsigned* __restrict__ pw, int n)
{
    int i = blockIdx.x * 256 + threadIdx.x;
    if (i < n) pw[i] = pack_hl(w[i]);
}

// ---------------- cln stats: per (b,p) mean/rsqrt over 256 channels ----------------
__global__ __launch_bounds__(256) void cln_stats_kernel(
    const float* __restrict__ x, float* __restrict__ rs, float* __restrict__ mrs)
{
    __shared__ double red[512];
    int t = threadIdx.x;
    int i = t & 63, q = t >> 6;
    int col = blockIdx.x * 64 + i;
    int b = col >> 12, p = col & 4095;
    const float* src = x + (size_t)b * NC * NP + (size_t)(q * 64) * NP + p;
    double s = 0.0, s2 = 0.0;
    #pragma unroll 8
    for (int c = 0; c < 64; c++) { float v = src[(size_t)c * NP]; s += v; s2 += (double)v * v; }
    red[q * 64 + i] = s; red[256 + q * 64 + i] = s2;
    __syncthreads();
    if (q == 0) {
        double S  = red[i] + red[64 + i] + red[128 + i] + red[192 + i];
        double S2 = red[256 + i] + red[320 + i] + red[384 + i] + red[448 + i];
        double mean = S * (1.0 / 256.0);
        double var = S2 * (1.0 / 256.0) - mean * mean;
        double r = 1.0 / sqrt(var + (double)CEPS);
        rs[col]  = (float)r;
        mrs[col] = (float)(mean * r);
    }
}

// ---------------- A/B fold constants ----------------
__global__ __launch_bounds__(256) void ab_kernel(
    const float* __restrict__ wq, const float* __restrict__ g, const float* __restrict__ bc,
    float* __restrict__ Aab, float* __restrict__ Bab)
{
    int o = blockIdx.x * 256 + threadIdx.x;
    if (o >= 768) return;
    double a = 0.0, bsum = 0.0;
    for (int c = 0; c < 256; c++) {
        double w = wq[o * 256 + c];
        a += w * (double)g[c];
        bsum += w * (double)bc[c];
    }
    Aab[o] = (float)a; Bab[o] = (float)bsum;
}

// ---------------- fused comb weight: W_fused = [W_comb_L @ W_out | W_comb_R] ----------
__global__ __launch_bounds__(256) void fuse_comb_kernel(
    const float* __restrict__ w_comb, const float* __restrict__ w_out,
    const float* __restrict__ b_out, const float* __restrict__ b_comb,
    unsigned* __restrict__ pwF, float* __restrict__ bF)
{
    int idx = blockIdx.x * 256 + threadIdx.x;   // 131072
    int o = idx >> 9, cc = idx & 511;
    float val;
    if (cc < 256) {
        double s = 0.0;
        for (int k = 0; k < 256; k++)
            s += (double)w_comb[o * 512 + k] * (double)w_out[k * 256 + cc];
        val = (float)s;
    } else {
        val = w_comb[o * 512 + cc];
    }
    pwF[idx] = pack_hl(val);
    if (idx < 256) {
        double s = 0.0;
        for (int k = 0; k < 256; k++)
            s += (double)w_comb[idx * 512 + k] * (double)b_out[k];
        bF[idx] = (float)(s + (double)b_comb[idx]);
    }
}

// ---------------- split-bf16 MFMA GEMM: 128o x 128p tile, 8 waves (32x64/wave) --------
// Double-buffered LDS, ONE barrier per K-step:
//   LOAD(k+1) -> MFMA(buf c) -> STORE(buf c^1) -> barrier
template<bool PACKO, bool PACKA, bool CLN, bool OBF16, bool BBF16>
__global__ __launch_bounds__(512) void gemm_mfma(
    const float* __restrict__ inA, int sA, int C1,
    const float* __restrict__ inB, int sB, int Ctot,
    const float* __restrict__ Wt, const float* __restrict__ bias,
    const float* __restrict__ resid, float* __restrict__ out, int sO, int O,
    const float* __restrict__ rs, const float* __restrict__ mrs,
    const float* __restrict__ Aab, const float* __restrict__ Bab,
    float* __restrict__ qrow, float* __restrict__ kheight)
{
    __shared__ __align__(16) unsigned short Ah[2][128 * 32], Al[2][128 * 32];
    __shared__ __align__(16) unsigned short Bh[2][128 * 32];
    __shared__ __align__(16) unsigned short Bl[2][BBF16 ? 16 : 128 * 32];

    // ---- XCD-batch swizzle ----
    const unsigned npb = gridDim.x * gridDim.y;
    unsigned lin = blockIdx.x + gridDim.x * (blockIdx.y + gridDim.y * blockIdx.z);
    unsigned low = lin & 7u, rest = lin >> 3;
    unsigned high = (rest >= npb) ? 1u : 0u;
    unsigned idx = rest - high * npb;
    const int b = (int)(low + 8u * high);
    const int o0 = (int)(idx / gridDim.x) * 128, p0 = (int)(idx % gridDim.x) * 128;

    const int t = threadIdx.x;
    const int l = t & 63, w = t >> 6;
    const int wr = w & 3, wc = w >> 2;
    const int g = l >> 4, l15 = l & 15;
    const int slotl = (l & 3) ^ ((l >> 2) & 3);

    f32x4 acc[2][4];
    #pragma unroll
    for (int m = 0; m < 2; m++)
        #pragma unroll
        for (int n = 0; n < 4; n++) acc[m][n] = (f32x4){0.f, 0.f, 0.f, 0.f};

    const int arow = t >> 2;
    const int ak8 = (t & 3) * 8;
    const int aslot = (arow & 3) ^ ((arow >> 2) & 3);
    const int aoff = arow * 64 + ((((ak8 >> 3)) ^ aslot) << 4);
    const int bp = t & 127;
    const int bhk = t >> 7;
    const int bslot = (bp & 3) ^ ((bp >> 2) & 3);
    const int boffst = bp * 64 + ((bhk ^ bslot) << 4);

    uint4 wa0, wa1;
    unsigned pb[8];

    #define LOAD_TILE(K0)                                                                 \
    {                                                                                     \
        const unsigned* wsrc = (const unsigned*)Wt + (size_t)(o0 + arow) * Ctot + (K0) + ak8; \
        wa0 = *(const uint4*)(wsrc);                                                      \
        wa1 = *(const uint4*)(wsrc + 4);                                                  \
        _Pragma("unroll")                                                                 \
        for (int q = 0; q < 4; q++) {                                                     \
            int c2 = bhk * 8 + q * 2;                                                     \
            int cc = (K0) + c2;                                                           \
            if constexpr (BBF16) {                                                        \
                const unsigned short* s16 = (cc < C1)                                     \
                    ? (const unsigned short*)inA + ((size_t)b * sA + cc) * (size_t)NP + p0 + bp \
                    : (const unsigned short*)inB + ((size_t)b * sB + (cc - C1)) * (size_t)NP + p0 + bp; \
                unsigned short v0 = s16[0];                                               \
                unsigned short v1 = s16[NP];                                              \
                pb[q] = (unsigned)v0 | ((unsigned)v1 << 16);                              \
            } else {                                                                      \
                const float* srcp = (cc < C1) ? inA + ((size_t)b * sA + cc) * (size_t)NP  \
                                              : inB + ((size_t)b * sB + (cc - C1)) * (size_t)NP; \
                pb[2 * q]     = __float_as_uint(srcp[p0 + bp]);                           \
                pb[2 * q + 1] = __float_as_uint(srcp[(size_t)NP + p0 + bp]);              \
            }                                                                             \
        }                                                                                 \
    }

    #define STORE_LDS(BUF)                                                                \
    {                                                                                     \
        char* cAh = (char*)Ah[BUF]; char* cAl = (char*)Al[BUF];                           \
        char* cBh = (char*)Bh[BUF]; char* cBl = (char*)Bl[BUF];                           \
        (void)cBl;                                                                        \
        if constexpr (PACKA) {                                                            \
            uint4 hq, lq;                                                                 \
            hq.x = __builtin_amdgcn_perm(wa0.y, wa0.x, 0x07060302u);                      \
            lq.x = __builtin_amdgcn_perm(wa0.y, wa0.x, 0x05040100u);                      \
            hq.y = __builtin_amdgcn_perm(wa0.w, wa0.z, 0x07060302u);                      \
            lq.y = __builtin_amdgcn_perm(wa0.w, wa0.z, 0x05040100u);                      \
            hq.z = __builtin_amdgcn_perm(wa1.y, wa1.x, 0x07060302u);                      \
            lq.z = __builtin_amdgcn_perm(wa1.y, wa1.x, 0x05040100u);                      \
            hq.w = __builtin_amdgcn_perm(wa1.w, wa1.z, 0x07060302u);                      \
            lq.w = __builtin_amdgcn_perm(wa1.w, wa1.z, 0x05040100u);                      \
            *(uint4*)(cAh + aoff) = hq;                                                   \
            *(uint4*)(cAl + aoff) = lq;                                                   \
        } else {                                                                          \
            ushort4 h0, l0, h1, l1;                                                       \
            split_rn(__uint_as_float(wa0.x), h0.x, l0.x);                                 \
            split_rn(__uint_as_float(wa0.y), h0.y, l0.y);                                 \
            split_rn(__uint_as_float(wa0.z), h0.z, l0.z);                                 \
            split_rn(__uint_as_float(wa0.w), h0.w, l0.w);                                 \
            split_rn(__uint_as_float(wa1.x), h1.x, l1.x);                                 \
            split_rn(__uint_as_float(wa1.y), h1.y, l1.y);                                 \
            split_rn(__uint_as_float(wa1.z), h1.z, l1.z);                                 \
            split_rn(__uint_as_float(wa1.w), h1.w, l1.w);                                 \
            *(ushort4*)(cAh + aoff) = h0; *(ushort4*)(cAh + aoff + 8) = h1;               \
            *(ushort4*)(cAl + aoff) = l0; *(ushort4*)(cAl + aoff + 8) = l1;               \
        }                                                                                 \
        if constexpr (BBF16) {                                                            \
            *(uint4*)(cBh + boffst) = (uint4){pb[0], pb[1], pb[2], pb[3]};                \
        } else {                                                                          \
            unsigned hp[4], lp[4];                                                        \
            _Pragma("unroll")                                                             \
            for (int q = 0; q < 4; q++) {                                                 \
                unsigned u0 = pb[2 * q], u1 = pb[2 * q + 1];                              \
                if constexpr (CLN) {                                                      \
                    unsigned short sh0, sl0, sh1, sl1;                                    \
                    split_rn(__uint_as_float(u0), sh0, sl0);                              \
                    split_rn(__uint_as_float(u1), sh1, sl1);                              \
                    hp[q] = (unsigned)sh0 | ((unsigned)sh1 << 16);                        \
                    lp[q] = (unsigned)sl0 | ((unsigned)sl1 << 16);                        \
                } else {                                                                  \
                    hp[q] = __builtin_amdgcn_perm(u1, u0, 0x07060302u);                   \
                    lp[q] = __builtin_amdgcn_perm(u1, u0, 0x05040100u);                   \
                }                                                                         \
            }                                                                             \
            *(uint4*)(cBh + boffst) = (uint4){hp[0], hp[1], hp[2], hp[3]};                \
            *(uint4*)(cBl + boffst) = (uint4){lp[0], lp[1], lp[2], lp[3]};                \
        }                                                                                 \
    }

    #define MFMA_STEP(BUF)                                                                \
    {                                                                                     \
        const char* cAh = (const char*)Ah[BUF]; const char* cAl = (const char*)Al[BUF];   \
        const char* cBh = (const char*)Bh[BUF]; const char* cBl = (const char*)Bl[BUF];   \
        (void)cBl;                                                                        \
        s16x8 ah[2], al[2];                                                               \
        _Pragma("unroll")                                                                 \
        for (int m = 0; m < 2; m++) {                                                     \
            int ao = (wr * 32 + m * 16 + l15) * 64 + ((g ^ slotl) << 4);                  \
            ah[m] = *(const s16x8*)(cAh + ao);                                            \
            al[m] = *(const s16x8*)(cAl + ao);                                            \
        }                                                                                 \
        _Pragma("unroll")                                                                 \
        for (int n = 0; n < 4; n++) {                                                     \
            int bo = (wc * 64 + n * 16 + l15) * 64 + ((g ^ slotl) << 4);                  \
            s16x8 bh = *(const s16x8*)(cBh + bo);                                         \
            if constexpr (BBF16) {                                                        \
                _Pragma("unroll")                                                         \
                for (int m = 0; m < 2; m++) {                                             \
                    acc[m][n] = __builtin_amdgcn_mfma_f32_16x16x32_bf16(ah[m], bh, acc[m][n], 0, 0, 0); \
                    acc[m][n] = __builtin_amdgcn_mfma_f32_16x16x32_bf16(al[m], bh, acc[m][n], 0, 0, 0); \
                }                                                                         \
            } else {                                                                      \
                s16x8 bl = *(const s16x8*)(cBl + bo);                                     \
                _Pragma("unroll")                                                         \
                for (int m = 0; m < 2; m++) {                                             \
                    acc[m][n] = __builtin_amdgcn_mfma_f32_16x16x32_bf16(ah[m], bh, acc[m][n], 0, 0, 0); \
                    acc[m][n] = __builtin_amdgcn_mfma_f32_16x16x32_bf16(ah[m], bl, acc[m][n], 0, 0, 0); \
                    acc[m][n] = __builtin_amdgcn_mfma_f32_16x16x32_bf16(al[m], bh, acc[m][n], 0, 0, 0); \
                }                                                                         \
            }                                                                             \
        }                                                                                 \
    }

    // prologue: tile 0 into buf0
    LOAD_TILE(0)
    STORE_LDS(0)
    __syncthreads();

    // K-steps come in pairs (Ctot % 64 == 0 for all call sites: 256, 512, 1024)
    for (int k0 = 0; k0 < Ctot; k0 += 64) {
        LOAD_TILE(k0 + 32)
        MFMA_STEP(0)
        STORE_LDS(1)
        __syncthreads();
        if (k0 + 64 < Ctot) {
            LOAD_TILE(k0 + 64)
            MFMA_STEP(1)
            STORE_LDS(0)
            __syncthreads();
        } else {
            MFMA_STEP(1)
        }
    }
    #undef LOAD_TILE
    #undef STORE_LDS
    #undef MFMA_STEP

    // ---- epilogue: D[row=(l>>4)*4+r][col=l&15] ----
    #pragma unroll
    for (int m = 0; m < 2; m++) {
        #pragma unroll
        for (int r = 0; r < 4; r++) {
            int orow = o0 + wr * 32 + m * 16 + g * 4 + r;
            float bs = (!CLN && bias) ? bias[orow] : 0.f;
            float Ao = CLN ? Aab[orow] : 0.f;
            float Bo = CLN ? Bab[orow] : 0.f;
            if constexpr (CLN) {
                float vv[4];
                #pragma unroll
                for (int n = 0; n < 4; n++) {
                    int pcol = p0 + wc * 64 + n * 16 + l15;
                    size_t cidx = (size_t)b * NP + pcol;
                    vv[n] = rs[cidx] * acc[m][n][r] - mrs[cidx] * Ao + Bo;
                }
                int which = orow >> 8;
                if (which < 2) {
                    float ss = vv[0] * vv[0] + vv[1] * vv[1] + vv[2] * vv[2] + vv[3] * vv[3];
                    ss += __shfl_xor(ss, 1); ss += __shfl_xor(ss, 2);
                    ss += __shfl_xor(ss, 4); ss += __shfl_xor(ss, 8);
                    float inv = 1.f / fmaxf(sqrtf(ss), 1e-12f);
                    float as = 0.f;
                    #pragma unroll
                    for (int n = 0; n < 4; n++) { vv[n] *= inv; as += fabsf(vv[n]); }
                    as += __shfl_xor(as, 1); as += __shfl_xor(as, 2);
                    as += __shfl_xor(as, 4); as += __shfl_xor(as, 8);
                    if (l15 == 0) {
                        int idx2 = orow & 255;
                        int head = idx2 >> 5, c = idx2 & 31;
                        int h = (p0 >> 6) + wc;
                        int rr = ((b << 3) + head) * 2048 + c * 64 + h;
                        (which == 0 ? qrow : kheight)[rr] = as;
                    }
                }
                #pragma unroll
                for (int n = 0; n < 4; n++) {
                    int pcol = p0 + wc * 64 + n * 16 + l15;
                    out[((size_t)b * sO + orow) * (size_t)NP + pcol] = vv[n];
                }
            } else {
                #pragma unroll
                for (int n = 0; n < 4; n++) {
                    int pcol = p0 + wc * 64 + n * 16 + l15;
                    float v = acc[m][n][r] + bs;
                    if (resid) v += resid[((size_t)b * O + orow) * (size_t)NP + pcol];
                    size_t oidx = ((size_t)b * sO + orow) * (size_t)NP + pcol;
                    if constexpr (OBF16)
                        ((unsigned short*)out)[oidx] = f2bf(v);
                    else
                        out[oidx] = PACKO ? packf(v) : v;
                }
            }
        }
    }
}

// ---------------- scores + top-k rows/cols + gather k (qprobe folded); exports idx ----
__global__ __launch_bounds__(64) void select_kernel(
    const float* __restrict__ qkv, const float* __restrict__ qrow,
    const float* __restrict__ kheight,
    float* __restrict__ ksel, int* __restrict__ hswsl)
{
    const int bh = blockIdx.x;
    const int b = bh >> 3, head = bh & 7;
    const int lane = threadIdx.x;
    __shared__ int hs[8], wsl[8];
    __shared__ float qp[32];
    if (lane < 32) {
        double s = 0.0;
        const float* qr = qrow + (size_t)bh * 2048 + lane * 64;
        for (int h = 0; h < 64; h++) s += qr[h];
        qp[lane] = (float)s;
    }
    __syncthreads();
    double scd = 0.0;
    for (int c = 0; c < 32; c++) scd += (double)qp[c] * kheight[((size_t)bh * 32 + c) * 64 + lane];
    float sc = (float)scd;
    for (int it = 0; it < 8; it++) {
        float v = sc; int id = lane;
        for (int off = 32; off; off >>= 1) {
            float ov = __shfl_xor(v, off); int oi = __shfl_xor(id, off);
            if (ov > v || (ov == v && oi < id)) { v = ov; id = oi; }
        }
        if (lane == 0) hs[it] = id;
        if (lane == id) sc = -3.4e38f;
    }
    __syncthreads();
    const float* kbase = qkv + ((size_t)b * 768 + 256 + head * 32) * NP;
    double sc2d = 0.0;
    for (int c = 0; c < 32; c++) {
        float kw = 0.f;
        for (int hi = 0; hi < 8; hi++)
            kw += fabsf(kbase[(size_t)c * NP + hs[hi] * 64 + lane]);
        sc2d += (double)qp[c] * kw;
    }
    float sc2 = (float)sc2d;
    for (int it = 0; it < 8; it++) {
        float v = sc2; int id = lane;
        for (int off = 32; off; off >>= 1) {
            float ov = __shfl_xor(v, off); int oi = __shfl_xor(id, off);
            if (ov > v || (ov == v && oi < id)) { v = ov; id = oi; }
        }
        if (lane == 0) wsl[it] = id;
        if (lane == id) sc2 = -3.4e38f;
    }
    __syncthreads();
    if (lane < 8) hswsl[bh * 16 + lane] = hs[lane];
    else if (lane < 16) hswsl[bh * 16 + lane] = wsl[lane - 8];
    int hi = lane >> 3, wi = lane & 7;
    int hh = hs[hi], ww = wsl[wi];
    for (int d = 0; d < 32; d++)
        ksel[((size_t)bh * 64 + lane) * 32 + d] = kbase[(size_t)d * NP + hh * 64 + ww];
}

// ---------------- lazy v: vsel[j][d] = rs*( (Wv g) . x[:,pos] ) - mrs*Av + Bv --------
__global__ __launch_bounds__(256) void vsel_kernel(
    const float* __restrict__ x, const float* __restrict__ w_qkv, const float* __restrict__ g,
    const int* __restrict__ hswsl, const float* __restrict__ rs, const float* __restrict__ mrs,
    const float* __restrict__ Aab, const float* __restrict__ Bab,
    float* __restrict__ vsel)
{
    __shared__ float Wg[32][257];
    __shared__ float xcol[16][257];
    __shared__ int pos_s[16];
    const int bh = blockIdx.y, b = bh >> 3, head = bh & 7;
    const int t = threadIdx.x;
    for (int i = t; i < 8192; i += 256) {
        int d = i >> 8, c = i & 255;
        Wg[d][c] = w_qkv[(size_t)(512 + head * 32 + d) * 256 + c] * g[c];
    }
    if (t < 16) {
        int j = blockIdx.x * 16 + t;
        int hh = hswsl[bh * 16 + (j >> 3)];
        int ww = hswsl[bh * 16 + 8 + (j & 7)];
        pos_s[t] = hh * 64 + ww;
    }
    __syncthreads();
    for (int i = t; i < 4096; i += 256) {
        int jj = i >> 8, c = i & 255;
        xcol[jj][c] = x[((size_t)b * 256 + c) * (size_t)NP + pos_s[jj]];
    }
    __syncthreads();
    const int l = t & 63, w = t >> 6;
    const int d = l & 31, ch = l >> 5;
    const float Av = Aab[512 + head * 32 + d];
    const float Bv = Bab[512 + head * 32 + d];
    for (int q = 0; q < 4; q++) {
        int jj = w * 4 + q;
        float s = 0.f;
        #pragma unroll
        for (int c = 0; c < 128; c++) s += Wg[d][ch * 128 + c] * xcol[jj][ch * 128 + c];
        s += __shfl_xor(s, 32);
        if (ch == 0) {
            int j = blockIdx.x * 16 + jj;
            size_t cidx = (size_t)b * NP + pos_s[jj];
            float val = rs[cidx] * s - mrs[cidx] * Av + Bv;
            vsel[((size_t)bh * 64 + j) * 32 + d] = val;
        }
    }
}

// ---------------- attention: writes compact bf16 ctx [b][256][NP] ----------------
__global__ __launch_bounds__(256) void attn_kernel(
    const float* __restrict__ qkv, const float* __restrict__ ksel, const float* __restrict__ vsel,
    unsigned short* __restrict__ ctxu)
{
    __shared__ __align__(16) float ks[64][32];
    __shared__ __align__(16) float vs[64][32];
    int bh = blockIdx.y, b = bh >> 3, head = bh & 7;
    int t = threadIdx.x;
    const float* kb = ksel + (size_t)bh * 2048;
    const float* vb = vsel + (size_t)bh * 2048;
    for (int i = 0; i < 8; i++) {
        ((float*)ks)[t + i * 256] = kb[t + i * 256];
        ((float*)vs)[t + i * 256] = vb[t + i * 256];
    }
    __syncthreads();
    int p = blockIdx.x * 256 + t;
    const float* qb = qkv + ((size_t)b * 768 + head * 32) * NP + p;
    unsigned short* ob = ctxu + ((size_t)b * 256 + head * 32) * NP + p;
    float q[32];
    #pragma unroll
    for (int d = 0; d < 32; d++) q[d] = qb[(size_t)d * NP];
    float s[64], m = -3.4e38f;
    for (int j = 0; j < 64; j++) {
        float dot = 0.f;
        #pragma unroll
        for (int d = 0; d < 32; d++) dot += q[d] * ks[j][d];
        s[j] = dot; m = fmaxf(m, dot);
    }
    float den = 0.f;
    for (int j = 0; j < 64; j++) { float e = __expf(s[j] - m); s[j] = e; den += e; }
    float o[32] = {};
    for (int j = 0; j < 64; j++) {
        float a = s[j];
        #pragma unroll
        for (int d = 0; d < 32; d++) o[d] += a * vs[j][d];
    }
    float r = 1.f / den;
    #pragma unroll
    for (int d = 0; d < 32; d++) ob[(size_t)d * NP] = f2bf(o[d] * r);
}

// ---------------- depthwise 3x3 on x; 2x8 stencil tile; padded LDS -------------------
__global__ __launch_bounds__(256) void dwconv_kernel(
    const float* __restrict__ in, const float* __restrict__ w, const float* __restrict__ bias,
    unsigned short* __restrict__ out, int Cn)
{
    __shared__ float pl[66][67];
    int bcb = blockIdx.x;
    int c = bcb % Cn;
    const float* src = in + (size_t)bcb * NP;
    unsigned* dst2 = (unsigned*)(out + (size_t)bcb * NP);
    int t = threadIdx.x;
    int rp = t >> 3, cg = t & 7;
    int r0 = rp * 2, c0 = cg * 8;
    if (t < 66) { pl[0][t] = 0.f; pl[65][t] = 0.f; }
    if (t >= 66 && t < 130) { int rr = t - 65; pl[rr][0] = 0.f; pl[rr][65] = 0.f; }
    float w9[9];
    #pragma unroll
    for (int k = 0; k < 9; k++) w9[k] = w[c * 9 + k];
    float bsv = bias[c];
    float4 a0 = *(const float4*)(src + r0 * 64 + c0);
    float4 a1 = *(const float4*)(src + r0 * 64 + c0 + 4);
    float4 b0 = *(const float4*)(src + (r0 + 1) * 64 + c0);
    float4 b1 = *(const float4*)(src + (r0 + 1) * 64 + c0 + 4);
    pl[r0 + 1][c0 + 1] = a0.x; pl[r0 + 1][c0 + 2] = a0.y;
    pl[r0 + 1][c0 + 3] = a0.z; pl[r0 + 1][c0 + 4] = a0.w;
    pl[r0 + 1][c0 + 5] = a1.x; pl[r0 + 1][c0 + 6] = a1.y;
    pl[r0 + 1][c0 + 7] = a1.z; pl[r0 + 1][c0 + 8] = a1.w;
    pl[r0 + 2][c0 + 1] = b0.x; pl[r0 + 2][c0 + 2] = b0.y;
    pl[r0 + 2][c0 + 3] = b0.z; pl[r0 + 2][c0 + 4] = b0.w;
    pl[r0 + 2][c0 + 5] = b1.x; pl[r0 + 2][c0 + 6] = b1.y;
    pl[r0 + 2][c0 + 7] = b1.z; pl[r0 + 2][c0 + 8] = b1.w;
    __syncthreads();
    float acc0[8], acc1[8];
    #pragma unroll
    for (int j = 0; j < 8; j++) { acc0[j] = bsv; acc1[j] = bsv; }
    #pragma unroll
    for (int dy = 0; dy < 4; dy++) {
        float tp[10];
        #pragma unroll
        for (int k = 0; k < 10; k++) tp[k] = pl[r0 + dy][c0 + k];
        if (dy < 3) {
            #pragma unroll
            for (int dx = 0; dx < 3; dx++)
                #pragma unroll
                for (int j = 0; j < 8; j++)
                    acc0[j] = fmaf(w9[dy * 3 + dx], tp[j + dx], acc0[j]);
        }
        if (dy >= 1) {
            #pragma unroll
            for (int dx = 0; dx < 3; dx++)
                #pragma unroll
                for (int j = 0; j < 8; j++)
                    acc1[j] = fmaf(w9[(dy - 1) * 3 + dx], tp[j + dx], acc1[j]);
        }
    }
    uint4 o0, o1;
    o0.x = (unsigned)f2bf(acc0[0]) | ((unsigned)f2bf(acc0[1]) << 16);
    o0.y = (unsigned)f2bf(acc0[2]) | ((unsigned)f2bf(acc0[3]) << 16);
    o0.z = (unsigned)f2bf(acc0[4]) | ((unsigned)f2bf(acc0[5]) << 16);
    o0.w = (unsigned)f2bf(acc0[6]) | ((unsigned)f2bf(acc0[7]) << 16);
    o1.x = (unsigned)f2bf(acc1[0]) | ((unsigned)f2bf(acc1[1]) << 16);
    o1.y = (unsigned)f2bf(acc1[2]) | ((unsigned)f2bf(acc1[3]) << 16);
    o1.z = (unsigned)f2bf(acc1[4]) | ((unsigned)f2bf(acc1[5]) << 16);
    o1.w = (unsigned)f2bf(acc1[6]) | ((unsigned)f2bf(acc1[7]) << 16);
    *(uint4*)(dst2 + ((r0 * 64 + c0) >> 1)) = o0;
    *(uint4*)(dst2 + (((r0 + 1) * 64 + c0) >> 1)) = o1;
}

// ---------------- fast gelu: A&S 7.1.25 3-term erf + hw rcp (max err ~2.5e-5) ---------
__device__ inline float gelu3(float x) {
    float z = x * 0.70710678118654752f;
    float a = fabsf(z);
    float t = __builtin_amdgcn_rcpf(fmaf(0.47047f, a, 1.0f));
    float p = t * (0.3480242f + t * (-0.0958798f + t * 0.7478556f));
    float e = __expf(-a * a);
    float r = 1.0f - p * e;                 // erf(|z|)
    float erfz = copysignf(r, z);
    return 0.5f * x * (1.0f + erfz);
}

// wave-shfl fp32 paired reduction + cross-wave LDS combine (2 barriers)
__device__ inline void wave_reduce2(float& a, float& b, float* sred, int t)
{
    #pragma unroll
    for (int off = 32; off; off >>= 1) { a += __shfl_xor(a, off); b += __shfl_xor(b, off); }
    int w = t >> 6, lane = t & 63;
    __syncthreads();
    if (lane == 0) { sred[w] = a; sred[4 + w] = b; }
    __syncthreads();
    a = sred[0] + sred[1] + sred[2] + sred[3];
    b = sred[4] + sred[5] + sred[6] + sred[7];
}

__device__ inline double block_reduce1(float s, double* red, int t)
{
    __syncthreads();
    red[t] = (double)s;
    __syncthreads();
    for (int st = 128; st; st >>= 1) {
        if (t < st) red[t] += red[t + st];
        __syncthreads();
    }
    return red[0];
}

// ---------------- fused FF on bf16 h; 2x8 stencil tile; shfl stats; cheap gelu --------
__global__ __launch_bounds__(256) void ff_fused_kernel(
    unsigned short* __restrict__ h, const float* __restrict__ w, const float* __restrict__ bias)
{
    __shared__ float pl[66][67];
    __shared__ float sred[8];
    int plane = blockIdx.x;
    int c = plane & (NFF - 1);
    const unsigned* h2 = (const unsigned*)(h + (size_t)plane * NP);
    unsigned* h2w = (unsigned*)(h + (size_t)plane * NP);
    int t = threadIdx.x;
    int rp = t >> 3, cg = t & 7;
    int r0 = rp * 2, c0 = cg * 8;
    if (t < 66) { pl[0][t] = 0.f; pl[65][t] = 0.f; }
    if (t >= 66 && t < 130) { int rr = t - 65; pl[rr][0] = 0.f; pl[rr][65] = 0.f; }

    uint4 u0 = *(const uint4*)(h2 + ((r0 * 64 + c0) >> 1));
    uint4 u1 = *(const uint4*)(h2 + (((r0 + 1) * 64 + c0) >> 1));
    float v[16]; float sf = 0.f, s2f = 0.f;
    {
        unsigned uu[8] = {u0.x, u0.y, u0.z, u0.w, u1.x, u1.y, u1.z, u1.w};
        #pragma unroll
        for (int i = 0; i < 8; i++) {
            float x0 = bf2f((unsigned short)(uu[i] & 0xffffu));
            float x1 = bf2f((unsigned short)(uu[i] >> 16));
            v[2 * i] = x0; v[2 * i + 1] = x1;
            sf += x0 + x1;
            s2f += x0 * x0 + x1 * x1;
        }
    }
    wave_reduce2(sf, s2f, sred, t);
    float mf = sf * (1.f / NP);
    float var = s2f * (1.f / NP) - mf * mf;
    float rs = rsqrtf(var + CEPS);

    float w9[9];
    #pragma unroll
    for (int k = 0; k < 9; k++) w9[k] = w[c * 9 + k];
    float bsv = bias[c];

    #pragma unroll
    for (int j = 0; j < 8; j++) {
        float gx = gelu3((v[j] - mf) * rs);
        v[j] = gx;
        pl[r0 + 1][c0 + 1 + j] = gx;
    }
    #pragma unroll
    for (int j = 0; j < 8; j++) {
        float gx = gelu3((v[8 + j] - mf) * rs);
        v[8 + j] = gx;
        pl[r0 + 2][c0 + 1 + j] = gx;
    }
    __syncthreads();

    float acc0[8], acc1[8];
    #pragma unroll
    for (int j = 0; j < 8; j++) { acc0[j] = bsv; acc1[j] = bsv; }
    #pragma unroll
    for (int dy = 0; dy < 4; dy++) {
        float tp[10];
        #pragma unroll
        for (int k = 0; k < 10; k++) tp[k] = pl[r0 + dy][c0 + k];
        if (dy < 3) {
            #pragma unroll
            for (int dx = 0; dx < 3; dx++)
                #pragma unroll
                for (int j = 0; j < 8; j++)
                    acc0[j] = fmaf(w9[dy * 3 + dx], tp[j + dx], acc0[j]);
        }
        if (dy >= 1) {
            #pragma unroll
            for (int dx = 0; dx < 3; dx++)
                #pragma unroll
                for (int j = 0; j < 8; j++)
                    acc1[j] = fmaf(w9[(dy - 1) * 3 + dx], tp[j + dx], acc1[j]);
        }
    }
    float sg = 0.f, s2g = 0.f;
    #pragma unroll
    for (int j = 0; j < 8; j++) {
        sg += acc0[j] + acc1[j];
        s2g += acc0[j] * acc0[j] + acc1[j] * acc1[j];
    }
    wave_reduce2(sg, s2g, sred, t);
    float mf2 = sg * (1.f / NP);
    float var2 = s2g * (1.f / NP) - mf2 * mf2;
    float rs2 = rsqrtf(var2 + CEPS);

    uint4 o0, o1;
    {
        float r00 = v[0] + gelu3((acc0[0] - mf2) * rs2);
        float r01 = v[1] + gelu3((acc0[1] - mf2) * rs2);
        float r02 = v[2] + gelu3((acc0[2] - mf2) * rs2);
        float r03 = v[3] + gelu3((acc0[3] - mf2) * rs2);
        float r04 = v[4] + gelu3((acc0[4] - mf2) * rs2);
        float r05 = v[5] + gelu3((acc0[5] - mf2) * rs2);
        float r06 = v[6] + gelu3((acc0[6] - mf2) * rs2);
        float r07 = v[7] + gelu3((acc0[7] - mf2) * rs2);
        o0.x = (unsigned)f2bf(r00) | ((unsigned)f2bf(r01) << 16);
        o0.y = (unsigned)f2bf(r02) | ((unsigned)f2bf(r03) << 16);
        o0.z = (unsigned)f2bf(r04) | ((unsigned)f2bf(r05) << 16);
        o0.w = (unsigned)f2bf(r06) | ((unsigned)f2bf(r07) << 16);
        float r10 = v[8]  + gelu3((acc1[0] - mf2) * rs2);
        float r11 = v[9]  + gelu3((acc1[1] - mf2) * rs2);
        float r12 = v[10] + gelu3((acc1[2] - mf2) * rs2);
        float r13 = v[11] + gelu3((acc1[3] - mf2) * rs2);
        float r14 = v[12] + gelu3((acc1[4] - mf2) * rs2);
        float r15 = v[13] + gelu3((acc1[5] - mf2) * rs2);
        float r16 = v[14] + gelu3((acc1[6] - mf2) * rs2);
        float r17 = v[15] + gelu3((acc1[7] - mf2) * rs2);
        o1.x = (unsigned)f2bf(r10) | ((unsigned)f2bf(r11) << 16);
        o1.y = (unsigned)f2bf(r12) | ((unsigned)f2bf(r13) << 16);
        o1.z = (unsigned)f2bf(r14) | ((unsigned)f2bf(r15) << 16);
        o1.w = (unsigned)f2bf(r16) | ((unsigned)f2bf(r17) << 16);
    }
    *(uint4*)(h2w + ((r0 * 64 + c0) >> 1)) = o0;
    *(uint4*)(h2w + (((r0 + 1) * 64 + c0) >> 1)) = o1;
}

// ---------------- final instance norm in place on d_out (2-pass centered, f64 tree) ---
__global__ __launch_bounds__(256) void in_final_kernel(float* __restrict__ y)
{
    __shared__ double red[256];
    size_t base = (size_t)blockIdx.x * NP;
    int t = threadIdx.x;
    float v[16]; float sf = 0.f;
    #pragma unroll
    for (int i = 0; i < 16; i++) { float x = y[base + t + i * 256]; v[i] = x; sf += x; }
    double S = block_reduce1(sf, red, t);
    float mf = (float)(S * (1.0 / NP));
    float s2f = 0.f;
    #pragma unroll
    for (int i = 0; i < 16; i++) { float d = v[i] - mf; v[i] = d; s2f += d * d; }
    double S2 = block_reduce1(s2f, red, t);
    float rs = (float)(1.0 / sqrt(S2 * (1.0 / NP) + (double)CEPS));
    #pragma unroll
    for (int i = 0; i < 16; i++)
        y[base + t + i * 256] = v[i] * rs;
}

extern "C" void kernel_launch(void* const* d_in, const int* in_sizes, int n_in,
                              void* d_out, int out_size, void* d_ws, size_t ws_size,
                              hipStream_t stream)
{
    const float* x      = (const float*)d_in[0];
    const float* g      = (const float*)d_in[1];
    const float* bc     = (const float*)d_in[2];
    const float* w_qkv  = (const float*)d_in[3];
    const float* w_out  = (const float*)d_in[4];
    const float* b_out  = (const float*)d_in[5];
    const float* w_dw   = (const float*)d_in[6];
    const float* b_dw   = (const float*)d_in[7];
    const float* w_comb = (const float*)d_in[8];
    const float* b_comb = (const float*)d_in[9];
    const float* w_ff1  = (const float*)d_in[10];
    const float* b_ff1  = (const float*)d_in[11];
    const float* w_ffdw = (const float*)d_in[12];
    const float* b_ffdw = (const float*)d_in[13];
    const float* w_ff2  = (const float*)d_in[14];
    const float* b_ff2  = (const float*)d_in[15];
    float* out = (float*)d_out;
    float* ws  = (float*)d_ws;

    const size_t S = (size_t)NB * NC * NP;   // 16,777,216 floats (64 MiB)
    float* qkv   = ws + S;
    unsigned short* h1u   = (unsigned short*)ws;
    unsigned short* ctxu  = (unsigned short*)(ws + 2097152);
    unsigned short* convu = (unsigned short*)(ws + S);
    unsigned short* Fbufu = (unsigned short*)out;
    float* qrow    = ws;                       // 262144
    float* kheight = qrow + 262144;            // 262144
    float* kselb   = kheight + 262144;         // 262144
    float* vselb   = kselb + 262144;           // ends at 1048576
    int*   hswsl   = (int*)(ws + 1048576);     // 2048 ints
    float* rs_a    = ws + 1052672;             // 65536
    float* mrs_a   = rs_a + 65536;             // 65536
    float* Aab     = mrs_a + 65536;            // 768
    float* Bab     = Aab + 768;                // 768
    unsigned* pw_qkv = (unsigned*)out;
    unsigned* pwF    = (unsigned*)ws;
    float*    bF     = ws + 131072;
    unsigned* pw_ff1 = (unsigned*)(ws + 2 * S);            // 262144 u32
    unsigned* pw_ff2 = (unsigned*)(ws + 2 * S) + 262144;   // 262144 u32

    size_t need = 4 * S * sizeof(float);
    if (ws_size < need) {
        float val = 1024.0f + (float)(ws_size >> 20);
        diag_fill<<<(out_size + 255) / 256, 256, 0, stream>>>(out, val, out_size);
        return;
    }

    // 0. prepack W_qkv*diag(g) for q,k rows; cln stats; fold constants
    pack_wg_kernel<<<512, 256, 0, stream>>>(w_qkv, g, pw_qkv, 512 * 256);
    cln_stats_kernel<<<1024, 256, 0, stream>>>(x, rs_a, mrs_a);
    ab_kernel<<<3, 256, 0, stream>>>(w_qkv, g, bc, Aab, Bab);
    // 2. q,k = fold( (W_qkv g) * x ) with fused l2norm + qrow/kheight  (O=512, lazy v)
    gemm_mfma<false, true, true, false, false><<<dim3(32, 4, NB), 512, 0, stream>>>(
        x, 256, 256, nullptr, 0, 256, (const float*)pw_qkv, nullptr, nullptr, qkv, 768, 512,
        rs_a, mrs_a, Aab, Bab, qrow, kheight);
    // 5. select: top-k + k gather + index export
    select_kernel<<<NBH, 64, 0, stream>>>(qkv, qrow, kheight, kselb, hswsl);
    // 5b. lazy v from x with cln fold
    vsel_kernel<<<dim3(4, NBH), 256, 0, stream>>>(x, w_qkv, g, hswsl, rs_a, mrs_a,
                                                  Aab, Bab, vselb);
    // 6. attention -> compact bf16 ctx
    attn_kernel<<<dim3(16, NBH), 256, 0, stream>>>(qkv, kselb, vselb, ctxu);
    // 7. fused comb weight -> packed; prepack ff1/ff2 weights into dead qkv tail
    fuse_comb_kernel<<<512, 256, 0, stream>>>(w_comb, w_out, b_out, b_comb, pwF, bF);
    pack_w_plain_kernel<<<1024, 256, 0, stream>>>(w_ff1, pw_ff1, 1024 * 256);
    pack_w_plain_kernel<<<1024, 256, 0, stream>>>(w_ff2, pw_ff2, 256 * 1024);
    // 8. conv branch -> compact bf16 (dead qkv space)
    dwconv_kernel<<<NB * NC, 256, 0, stream>>>(x, w_dw, b_dw, convu, NC);
    // 9. attn_out = W_fused * [ctx; conv] (bf16 B, 2-MFMA) + b_fused + x -> bf16 d_out
    gemm_mfma<false, true, false, true, true><<<dim3(32, 2, NB), 512, 0, stream>>>(
        (const float*)ctxu, 256, 256, (const float*)convu, 256, 512,
        (const float*)pwF, bF, x, (float*)Fbufu, 256, 256,
        nullptr, nullptr, nullptr, nullptr, nullptr, nullptr);
    // 10. h1 = (pw_ff1) * attn_out (bf16 B, 2-MFMA, packed A) + b_ff1 -> bf16 ws[0,2S)
    gemm_mfma<false, true, false, true, true><<<dim3(32, 8, NB), 512, 0, stream>>>(
        (const float*)Fbufu, 256, 256, nullptr, 0, 256, (const float*)pw_ff1, b_ff1, nullptr,
        (float*)h1u, 1024, 1024, nullptr, nullptr, nullptr, nullptr, nullptr, nullptr);
    // 11. fused FF on bf16 h1 (in place)
    ff_fused_kernel<<<NB * NFF, 256, 0, stream>>>(h1u, w_ffdw, b_ffdw);
    // 12. y = (pw_ff2) * h1 (bf16 B, 2-MFMA, packed A) + b_ff2 -> d_out fp32
    gemm_mfma<false, true, false, false, true><<<dim3(32, 2, NB), 512, 0, stream>>>(
        (const float*)h1u, 1024, 1024, nullptr, 0, 1024, (const float*)pw_ff2, b_ff2, nullptr,
        out, 256, 256, nullptr, nullptr, nullptr, nullptr, nullptr, nullptr);
    // 13. final instance norm
    in_final_kernel<<<NB * NC, 256, 0, stream>>>(out);
}

// Round 26
// 692.356 us; speedup vs baseline: 1.0763x; 1.0763x over previous
//
#include <hip/hip_runtime.h>
#include <math.h>

#define NB 16
#define NC 256
#define NP 4096      // 64*64
#define NHEADS 8
#define NDH 32
#define NBH 128
#define NFF 1024
#define CEPS 1e-5f

typedef short s16x8 __attribute__((ext_vector_type(8)));
typedef float f32x4 __attribute__((ext_vector_type(4)));

// ---------------- diagnostic fill (guard trip) ----------------
__global__ __launch_bounds__(256) void diag_fill(float* __restrict__ out, float val, int n)
{
    int i = blockIdx.x * 256 + threadIdx.x;
    if (i < n) out[i] = val;
}

// ---------------- bf16 split helpers ----------------
__device__ inline unsigned short f2bf(float f) {
    unsigned u = __float_as_uint(f);
    return (unsigned short)((u + 0x7FFFu + ((u >> 16) & 1u)) >> 16);
}
__device__ inline float bf2f(unsigned short h) { return __uint_as_float(((unsigned)h) << 16); }
__device__ inline void split2(float f, unsigned short& hi, unsigned short& lo) {
    hi = f2bf(f);
    lo = f2bf(f - bf2f(hi));
}
// fast round-to-nearest split (6 ops)
__device__ inline void split_rn(float f, unsigned short& hi, unsigned short& lo) {
    unsigned u = __float_as_uint(f);
    unsigned tt = u + 0x8000u;
    hi = (unsigned short)(tt >> 16);
    float r = f - __uint_as_float(tt & 0xffff0000u);
    lo = (unsigned short)((__float_as_uint(r) + 0x8000u) >> 16);
}
// packed: (hi<<16)|lo
__device__ inline unsigned pack_hl(float f) {
    unsigned short h, lo; split2(f, h, lo);
    return ((unsigned)h << 16) | (unsigned)lo;
}
__device__ inline float packf(float f) { return __uint_as_float(pack_hl(f)); }

// ---------------- weight prepack with channel gain: pw = pack(w[o,c]*g[c]) ----------
__global__ __launch_bounds__(256) void pack_wg_kernel(
    const float* __restrict__ w, const float* __restrict__ g,
    unsigned* __restrict__ pw, int n)
{
    int i = blockIdx.x * 256 + threadIdx.x;
    if (i < n) pw[i] = pack_hl(w[i] * g[i & 255]);
}

// ---------------- plain weight prepack: pw = pack(w[i]) ----------
__global__ __launch_bounds__(256) void pack_w_plain_kernel(
    const float* __restrict__ w, unsigned* __restrict__ pw, int n)
{
    int i = blockIdx.x * 256 + threadIdx.x;
    if (i < n) pw[i] = pack_hl(w[i]);
}

// ---------------- cln stats: per (b,p) mean/rsqrt over 256 channels ----------------
__global__ __launch_bounds__(256) void cln_stats_kernel(
    const float* __restrict__ x, float* __restrict__ rs, float* __restrict__ mrs)
{
    __shared__ double red[512];
    int t = threadIdx.x;
    int i = t & 63, q = t >> 6;
    int col = blockIdx.x * 64 + i;
    int b = col >> 12, p = col & 4095;
    const float* src = x + (size_t)b * NC * NP + (size_t)(q * 64) * NP + p;
    double s = 0.0, s2 = 0.0;
    #pragma unroll 8
    for (int c = 0; c < 64; c++) { float v = src[(size_t)c * NP]; s += v; s2 += (double)v * v; }
    red[q * 64 + i] = s; red[256 + q * 64 + i] = s2;
    __syncthreads();
    if (q == 0) {
        double S  = red[i] + red[64 + i] + red[128 + i] + red[192 + i];
        double S2 = red[256 + i] + red[320 + i] + red[384 + i] + red[448 + i];
        double mean = S * (1.0 / 256.0);
        double var = S2 * (1.0 / 256.0) - mean * mean;
        double r = 1.0 / sqrt(var + (double)CEPS);
        rs[col]  = (float)r;
        mrs[col] = (float)(mean * r);
    }
}

// ---------------- A/B fold constants ----------------
__global__ __launch_bounds__(256) void ab_kernel(
    const float* __restrict__ wq, const float* __restrict__ g, const float* __restrict__ bc,
    float* __restrict__ Aab, float* __restrict__ Bab)
{
    int o = blockIdx.x * 256 + threadIdx.x;
    if (o >= 768) return;
    double a = 0.0, bsum = 0.0;
    for (int c = 0; c < 256; c++) {
        double w = wq[o * 256 + c];
        a += w * (double)g[c];
        bsum += w * (double)bc[c];
    }
    Aab[o] = (float)a; Bab[o] = (float)bsum;
}

// ---------------- fused comb weight: W_fused = [W_comb_L @ W_out | W_comb_R] ----------
__global__ __launch_bounds__(256) void fuse_comb_kernel(
    const float* __restrict__ w_comb, const float* __restrict__ w_out,
    const float* __restrict__ b_out, const float* __restrict__ b_comb,
    unsigned* __restrict__ pwF, float* __restrict__ bF)
{
    int idx = blockIdx.x * 256 + threadIdx.x;   // 131072
    int o = idx >> 9, cc = idx & 511;
    float val;
    if (cc < 256) {
        double s = 0.0;
        for (int k = 0; k < 256; k++)
            s += (double)w_comb[o * 512 + k] * (double)w_out[k * 256 + cc];
        val = (float)s;
    } else {
        val = w_comb[o * 512 + cc];
    }
    pwF[idx] = pack_hl(val);
    if (idx < 256) {
        double s = 0.0;
        for (int k = 0; k < 256; k++)
            s += (double)w_comb[idx * 512 + k] * (double)b_out[k];
        bF[idx] = (float)(s + (double)b_comb[idx]);
    }
}

// ---------------- split-bf16 MFMA GEMM: 128o x 128p tile, 8 waves (32x64/wave) --------
template<bool PACKO, bool PACKA, bool CLN, bool OBF16, bool BBF16>
__global__ __launch_bounds__(512) void gemm_mfma(
    const float* __restrict__ inA, int sA, int C1,
    const float* __restrict__ inB, int sB, int Ctot,
    const float* __restrict__ Wt, const float* __restrict__ bias,
    const float* __restrict__ resid, float* __restrict__ out, int sO, int O,
    const float* __restrict__ rs, const float* __restrict__ mrs,
    const float* __restrict__ Aab, const float* __restrict__ Bab,
    float* __restrict__ qrow, float* __restrict__ kheight)
{
    __shared__ __align__(16) unsigned short Ah[128 * 32], Al[128 * 32];
    __shared__ __align__(16) unsigned short Bh[128 * 32];
    __shared__ __align__(16) unsigned short Bl[BBF16 ? 16 : 128 * 32];
    char* cAh = (char*)Ah; char* cAl = (char*)Al;
    char* cBh = (char*)Bh; char* cBl = (char*)Bl;

    // ---- XCD-batch swizzle ----
    const unsigned npb = gridDim.x * gridDim.y;
    unsigned lin = blockIdx.x + gridDim.x * (blockIdx.y + gridDim.y * blockIdx.z);
    unsigned low = lin & 7u, rest = lin >> 3;
    unsigned high = (rest >= npb) ? 1u : 0u;
    unsigned idx = rest - high * npb;
    const int b = (int)(low + 8u * high);
    const int o0 = (int)(idx / gridDim.x) * 128, p0 = (int)(idx % gridDim.x) * 128;

    const int t = threadIdx.x;
    const int l = t & 63, w = t >> 6;
    const int wr = w & 3, wc = w >> 2;
    const int g = l >> 4, l15 = l & 15;
    const int slotl = (l & 3) ^ ((l >> 2) & 3);

    f32x4 acc[2][4];
    #pragma unroll
    for (int m = 0; m < 2; m++)
        #pragma unroll
        for (int n = 0; n < 4; n++) acc[m][n] = (f32x4){0.f, 0.f, 0.f, 0.f};

    const int arow = t >> 2;
    const int ak8 = (t & 3) * 8;
    const int aslot = (arow & 3) ^ ((arow >> 2) & 3);
    const int aoff = arow * 64 + ((((ak8 >> 3)) ^ aslot) << 4);
    const int bp = t & 127;
    const int bhk = t >> 7;
    const int bslot = (bp & 3) ^ ((bp >> 2) & 3);
    const int boffst = bp * 64 + ((bhk ^ bslot) << 4);

    uint4 wa0, wa1;
    unsigned pb[8];

    #define LOAD_TILE(K0)                                                                 \
    {                                                                                     \
        const unsigned* wsrc = (const unsigned*)Wt + (size_t)(o0 + arow) * Ctot + (K0) + ak8; \
        wa0 = *(const uint4*)(wsrc);                                                      \
        wa1 = *(const uint4*)(wsrc + 4);                                                  \
        _Pragma("unroll")                                                                 \
        for (int q = 0; q < 4; q++) {                                                     \
            int c2 = bhk * 8 + q * 2;                                                     \
            int cc = (K0) + c2;                                                           \
            if constexpr (BBF16) {                                                        \
                const unsigned short* s16 = (cc < C1)                                     \
                    ? (const unsigned short*)inA + ((size_t)b * sA + cc) * (size_t)NP + p0 + bp \
                    : (const unsigned short*)inB + ((size_t)b * sB + (cc - C1)) * (size_t)NP + p0 + bp; \
                unsigned short v0 = s16[0];                                               \
                unsigned short v1 = s16[NP];                                              \
                pb[q] = (unsigned)v0 | ((unsigned)v1 << 16);                              \
            } else {                                                                      \
                const float* srcp = (cc < C1) ? inA + ((size_t)b * sA + cc) * (size_t)NP  \
                                              : inB + ((size_t)b * sB + (cc - C1)) * (size_t)NP; \
                pb[2 * q]     = __float_as_uint(srcp[p0 + bp]);                           \
                pb[2 * q + 1] = __float_as_uint(srcp[(size_t)NP + p0 + bp]);              \
            }                                                                             \
        }                                                                                 \
    }

    #define STORE_LDS()                                                                   \
    {                                                                                     \
        if constexpr (PACKA) {                                                            \
            uint4 hq, lq;                                                                 \
            hq.x = __builtin_amdgcn_perm(wa0.y, wa0.x, 0x07060302u);                      \
            lq.x = __builtin_amdgcn_perm(wa0.y, wa0.x, 0x05040100u);                      \
            hq.y = __builtin_amdgcn_perm(wa0.w, wa0.z, 0x07060302u);                      \
            lq.y = __builtin_amdgcn_perm(wa0.w, wa0.z, 0x05040100u);                      \
            hq.z = __builtin_amdgcn_perm(wa1.y, wa1.x, 0x07060302u);                      \
            lq.z = __builtin_amdgcn_perm(wa1.y, wa1.x, 0x05040100u);                      \
            hq.w = __builtin_amdgcn_perm(wa1.w, wa1.z, 0x07060302u);                      \
            lq.w = __builtin_amdgcn_perm(wa1.w, wa1.z, 0x05040100u);                      \
            *(uint4*)(cAh + aoff) = hq;                                                   \
            *(uint4*)(cAl + aoff) = lq;                                                   \
        } else {                                                                          \
            ushort4 h0, l0, h1, l1;                                                       \
            split_rn(__uint_as_float(wa0.x), h0.x, l0.x);                                 \
            split_rn(__uint_as_float(wa0.y), h0.y, l0.y);                                 \
            split_rn(__uint_as_float(wa0.z), h0.z, l0.z);                                 \
            split_rn(__uint_as_float(wa0.w), h0.w, l0.w);                                 \
            split_rn(__uint_as_float(wa1.x), h1.x, l1.x);                                 \
            split_rn(__uint_as_float(wa1.y), h1.y, l1.y);                                 \
            split_rn(__uint_as_float(wa1.z), h1.z, l1.z);                                 \
            split_rn(__uint_as_float(wa1.w), h1.w, l1.w);                                 \
            *(ushort4*)(cAh + aoff) = h0; *(ushort4*)(cAh + aoff + 8) = h1;               \
            *(ushort4*)(cAl + aoff) = l0; *(ushort4*)(cAl + aoff + 8) = l1;               \
        }                                                                                 \
        if constexpr (BBF16) {                                                            \
            *(uint4*)(cBh + boffst) = (uint4){pb[0], pb[1], pb[2], pb[3]};                \
        } else {                                                                          \
            unsigned hp[4], lp[4];                                                        \
            _Pragma("unroll")                                                             \
            for (int q = 0; q < 4; q++) {                                                 \
                unsigned u0 = pb[2 * q], u1 = pb[2 * q + 1];                              \
                if constexpr (CLN) {                                                      \
                    unsigned short sh0, sl0, sh1, sl1;                                    \
                    split_rn(__uint_as_float(u0), sh0, sl0);                              \
                    split_rn(__uint_as_float(u1), sh1, sl1);                              \
                    hp[q] = (unsigned)sh0 | ((unsigned)sh1 << 16);                        \
                    lp[q] = (unsigned)sl0 | ((unsigned)sl1 << 16);                        \
                } else {                                                                  \
                    hp[q] = __builtin_amdgcn_perm(u1, u0, 0x07060302u);                   \
                    lp[q] = __builtin_amdgcn_perm(u1, u0, 0x05040100u);                   \
                }                                                                         \
            }                                                                             \
            *(uint4*)(cBh + boffst) = (uint4){hp[0], hp[1], hp[2], hp[3]};                \
            *(uint4*)(cBl + boffst) = (uint4){lp[0], lp[1], lp[2], lp[3]};                \
        }                                                                                 \
    }

    LOAD_TILE(0)

    for (int k0 = 0; k0 < Ctot; k0 += 32) {
        if (k0) __syncthreads();
        STORE_LDS()
        __syncthreads();
        if (k0 + 32 < Ctot) LOAD_TILE(k0 + 32)

        s16x8 ah[2], al[2];
        #pragma unroll
        for (int m = 0; m < 2; m++) {
            int ao = (wr * 32 + m * 16 + l15) * 64 + ((g ^ slotl) << 4);
            ah[m] = *(const s16x8*)(cAh + ao);
            al[m] = *(const s16x8*)(cAl + ao);
        }
        #pragma unroll
        for (int n = 0; n < 4; n++) {
            int bo = (wc * 64 + n * 16 + l15) * 64 + ((g ^ slotl) << 4);
            s16x8 bh = *(const s16x8*)(cBh + bo);
            if constexpr (BBF16) {
                #pragma unroll
                for (int m = 0; m < 2; m++) {
                    acc[m][n] = __builtin_amdgcn_mfma_f32_16x16x32_bf16(ah[m], bh, acc[m][n], 0, 0, 0);
                    acc[m][n] = __builtin_amdgcn_mfma_f32_16x16x32_bf16(al[m], bh, acc[m][n], 0, 0, 0);
                }
            } else {
                s16x8 bl = *(const s16x8*)(cBl + bo);
                #pragma unroll
                for (int m = 0; m < 2; m++) {
                    acc[m][n] = __builtin_amdgcn_mfma_f32_16x16x32_bf16(ah[m], bh, acc[m][n], 0, 0, 0);
                    acc[m][n] = __builtin_amdgcn_mfma_f32_16x16x32_bf16(ah[m], bl, acc[m][n], 0, 0, 0);
                    acc[m][n] = __builtin_amdgcn_mfma_f32_16x16x32_bf16(al[m], bh, acc[m][n], 0, 0, 0);
                }
            }
        }
    }
    #undef LOAD_TILE
    #undef STORE_LDS

    // ---- epilogue: D[row=(l>>4)*4+r][col=l&15] ----
    #pragma unroll
    for (int m = 0; m < 2; m++) {
        #pragma unroll
        for (int r = 0; r < 4; r++) {
            int orow = o0 + wr * 32 + m * 16 + g * 4 + r;
            float bs = (!CLN && bias) ? bias[orow] : 0.f;
            float Ao = CLN ? Aab[orow] : 0.f;
            float Bo = CLN ? Bab[orow] : 0.f;
            if constexpr (CLN) {
                float vv[4];
                #pragma unroll
                for (int n = 0; n < 4; n++) {
                    int pcol = p0 + wc * 64 + n * 16 + l15;
                    size_t cidx = (size_t)b * NP + pcol;
                    vv[n] = rs[cidx] * acc[m][n][r] - mrs[cidx] * Ao + Bo;
                }
                int which = orow >> 8;
                if (which < 2) {
                    float ss = vv[0] * vv[0] + vv[1] * vv[1] + vv[2] * vv[2] + vv[3] * vv[3];
                    ss += __shfl_xor(ss, 1); ss += __shfl_xor(ss, 2);
                    ss += __shfl_xor(ss, 4); ss += __shfl_xor(ss, 8);
                    float inv = 1.f / fmaxf(sqrtf(ss), 1e-12f);
                    float as = 0.f;
                    #pragma unroll
                    for (int n = 0; n < 4; n++) { vv[n] *= inv; as += fabsf(vv[n]); }
                    as += __shfl_xor(as, 1); as += __shfl_xor(as, 2);
                    as += __shfl_xor(as, 4); as += __shfl_xor(as, 8);
                    if (l15 == 0) {
                        int idx2 = orow & 255;
                        int head = idx2 >> 5, c = idx2 & 31;
                        int h = (p0 >> 6) + wc;
                        int rr = ((b << 3) + head) * 2048 + c * 64 + h;
                        (which == 0 ? qrow : kheight)[rr] = as;
                    }
                }
                #pragma unroll
                for (int n = 0; n < 4; n++) {
                    int pcol = p0 + wc * 64 + n * 16 + l15;
                    out[((size_t)b * sO + orow) * (size_t)NP + pcol] = vv[n];
                }
            } else {
                #pragma unroll
                for (int n = 0; n < 4; n++) {
                    int pcol = p0 + wc * 64 + n * 16 + l15;
                    float v = acc[m][n][r] + bs;
                    if (resid) v += resid[((size_t)b * O + orow) * (size_t)NP + pcol];
                    size_t oidx = ((size_t)b * sO + orow) * (size_t)NP + pcol;
                    if constexpr (OBF16)
                        ((unsigned short*)out)[oidx] = f2bf(v);
                    else
                        out[oidx] = PACKO ? packf(v) : v;
                }
            }
        }
    }
}

// ---------------- scores + top-k rows/cols + gather k (qprobe folded); exports idx ----
__global__ __launch_bounds__(64) void select_kernel(
    const float* __restrict__ qkv, const float* __restrict__ qrow,
    const float* __restrict__ kheight,
    float* __restrict__ ksel, int* __restrict__ hswsl)
{
    const int bh = blockIdx.x;
    const int b = bh >> 3, head = bh & 7;
    const int lane = threadIdx.x;
    __shared__ int hs[8], wsl[8];
    __shared__ float qp[32];
    if (lane < 32) {
        double s = 0.0;
        const float* qr = qrow + (size_t)bh * 2048 + lane * 64;
        for (int h = 0; h < 64; h++) s += qr[h];
        qp[lane] = (float)s;
    }
    __syncthreads();
    double scd = 0.0;
    for (int c = 0; c < 32; c++) scd += (double)qp[c] * kheight[((size_t)bh * 32 + c) * 64 + lane];
    float sc = (float)scd;
    for (int it = 0; it < 8; it++) {
        float v = sc; int id = lane;
        for (int off = 32; off; off >>= 1) {
            float ov = __shfl_xor(v, off); int oi = __shfl_xor(id, off);
            if (ov > v || (ov == v && oi < id)) { v = ov; id = oi; }
        }
        if (lane == 0) hs[it] = id;
        if (lane == id) sc = -3.4e38f;
    }
    __syncthreads();
    const float* kbase = qkv + ((size_t)b * 768 + 256 + head * 32) * NP;
    double sc2d = 0.0;
    for (int c = 0; c < 32; c++) {
        float kw = 0.f;
        for (int hi = 0; hi < 8; hi++)
            kw += fabsf(kbase[(size_t)c * NP + hs[hi] * 64 + lane]);
        sc2d += (double)qp[c] * kw;
    }
    float sc2 = (float)sc2d;
    for (int it = 0; it < 8; it++) {
        float v = sc2; int id = lane;
        for (int off = 32; off; off >>= 1) {
            float ov = __shfl_xor(v, off); int oi = __shfl_xor(id, off);
            if (ov > v || (ov == v && oi < id)) { v = ov; id = oi; }
        }
        if (lane == 0) wsl[it] = id;
        if (lane == id) sc2 = -3.4e38f;
    }
    __syncthreads();
    if (lane < 8) hswsl[bh * 16 + lane] = hs[lane];
    else if (lane < 16) hswsl[bh * 16 + lane] = wsl[lane - 8];
    int hi = lane >> 3, wi = lane & 7;
    int hh = hs[hi], ww = wsl[wi];
    for (int d = 0; d < 32; d++)
        ksel[((size_t)bh * 64 + lane) * 32 + d] = kbase[(size_t)d * NP + hh * 64 + ww];
}

// ---------------- lazy v: vsel[j][d] = rs*( (Wv g) . x[:,pos] ) - mrs*Av + Bv --------
__global__ __launch_bounds__(256) void vsel_kernel(
    const float* __restrict__ x, const float* __restrict__ w_qkv, const float* __restrict__ g,
    const int* __restrict__ hswsl, const float* __restrict__ rs, const float* __restrict__ mrs,
    const float* __restrict__ Aab, const float* __restrict__ Bab,
    float* __restrict__ vsel)
{
    __shared__ float Wg[32][257];
    __shared__ float xcol[16][257];
    __shared__ int pos_s[16];
    const int bh = blockIdx.y, b = bh >> 3, head = bh & 7;
    const int t = threadIdx.x;
    for (int i = t; i < 8192; i += 256) {
        int d = i >> 8, c = i & 255;
        Wg[d][c] = w_qkv[(size_t)(512 + head * 32 + d) * 256 + c] * g[c];
    }
    if (t < 16) {
        int j = blockIdx.x * 16 + t;
        int hh = hswsl[bh * 16 + (j >> 3)];
        int ww = hswsl[bh * 16 + 8 + (j & 7)];
        pos_s[t] = hh * 64 + ww;
    }
    __syncthreads();
    for (int i = t; i < 4096; i += 256) {
        int jj = i >> 8, c = i & 255;
        xcol[jj][c] = x[((size_t)b * 256 + c) * (size_t)NP + pos_s[jj]];
    }
    __syncthreads();
    const int l = t & 63, w = t >> 6;
    const int d = l & 31, ch = l >> 5;
    const float Av = Aab[512 + head * 32 + d];
    const float Bv = Bab[512 + head * 32 + d];
    for (int q = 0; q < 4; q++) {
        int jj = w * 4 + q;
        float s = 0.f;
        #pragma unroll
        for (int c = 0; c < 128; c++) s += Wg[d][ch * 128 + c] * xcol[jj][ch * 128 + c];
        s += __shfl_xor(s, 32);
        if (ch == 0) {
            int j = blockIdx.x * 16 + jj;
            size_t cidx = (size_t)b * NP + pos_s[jj];
            float val = rs[cidx] * s - mrs[cidx] * Av + Bv;
            vsel[((size_t)bh * 64 + j) * 32 + d] = val;
        }
    }
}

// ---------------- attention: writes compact bf16 ctx [b][256][NP] ----------------
__global__ __launch_bounds__(256) void attn_kernel(
    const float* __restrict__ qkv, const float* __restrict__ ksel, const float* __restrict__ vsel,
    unsigned short* __restrict__ ctxu)
{
    __shared__ __align__(16) float ks[64][32];
    __shared__ __align__(16) float vs[64][32];
    int bh = blockIdx.y, b = bh >> 3, head = bh & 7;
    int t = threadIdx.x;
    const float* kb = ksel + (size_t)bh * 2048;
    const float* vb = vsel + (size_t)bh * 2048;
    for (int i = 0; i < 8; i++) {
        ((float*)ks)[t + i * 256] = kb[t + i * 256];
        ((float*)vs)[t + i * 256] = vb[t + i * 256];
    }
    __syncthreads();
    int p = blockIdx.x * 256 + t;
    const float* qb = qkv + ((size_t)b * 768 + head * 32) * NP + p;
    unsigned short* ob = ctxu + ((size_t)b * 256 + head * 32) * NP + p;
    float q[32];
    #pragma unroll
    for (int d = 0; d < 32; d++) q[d] = qb[(size_t)d * NP];
    float s[64], m = -3.4e38f;
    for (int j = 0; j < 64; j++) {
        float dot = 0.f;
        #pragma unroll
        for (int d = 0; d < 32; d++) dot += q[d] * ks[j][d];
        s[j] = dot; m = fmaxf(m, dot);
    }
    float den = 0.f;
    for (int j = 0; j < 64; j++) { float e = __expf(s[j] - m); s[j] = e; den += e; }
    float o[32] = {};
    for (int j = 0; j < 64; j++) {
        float a = s[j];
        #pragma unroll
        for (int d = 0; d < 32; d++) o[d] += a * vs[j][d];
    }
    float r = 1.f / den;
    #pragma unroll
    for (int d = 0; d < 32; d++) ob[(size_t)d * NP] = f2bf(o[d] * r);
}

// ---------------- depthwise 3x3 on x; 2x8 stencil tile; padded LDS -------------------
__global__ __launch_bounds__(256) void dwconv_kernel(
    const float* __restrict__ in, const float* __restrict__ w, const float* __restrict__ bias,
    unsigned short* __restrict__ out, int Cn)
{
    __shared__ float pl[66][67];
    int bcb = blockIdx.x;
    int c = bcb % Cn;
    const float* src = in + (size_t)bcb * NP;
    unsigned* dst2 = (unsigned*)(out + (size_t)bcb * NP);
    int t = threadIdx.x;
    int rp = t >> 3, cg = t & 7;
    int r0 = rp * 2, c0 = cg * 8;
    if (t < 66) { pl[0][t] = 0.f; pl[65][t] = 0.f; }
    if (t >= 66 && t < 130) { int rr = t - 65; pl[rr][0] = 0.f; pl[rr][65] = 0.f; }
    float w9[9];
    #pragma unroll
    for (int k = 0; k < 9; k++) w9[k] = w[c * 9 + k];
    float bsv = bias[c];
    float4 a0 = *(const float4*)(src + r0 * 64 + c0);
    float4 a1 = *(const float4*)(src + r0 * 64 + c0 + 4);
    float4 b0 = *(const float4*)(src + (r0 + 1) * 64 + c0);
    float4 b1 = *(const float4*)(src + (r0 + 1) * 64 + c0 + 4);
    pl[r0 + 1][c0 + 1] = a0.x; pl[r0 + 1][c0 + 2] = a0.y;
    pl[r0 + 1][c0 + 3] = a0.z; pl[r0 + 1][c0 + 4] = a0.w;
    pl[r0 + 1][c0 + 5] = a1.x; pl[r0 + 1][c0 + 6] = a1.y;
    pl[r0 + 1][c0 + 7] = a1.z; pl[r0 + 1][c0 + 8] = a1.w;
    pl[r0 + 2][c0 + 1] = b0.x; pl[r0 + 2][c0 + 2] = b0.y;
    pl[r0 + 2][c0 + 3] = b0.z; pl[r0 + 2][c0 + 4] = b0.w;
    pl[r0 + 2][c0 + 5] = b1.x; pl[r0 + 2][c0 + 6] = b1.y;
    pl[r0 + 2][c0 + 7] = b1.z; pl[r0 + 2][c0 + 8] = b1.w;
    __syncthreads();
    float acc0[8], acc1[8];
    #pragma unroll
    for (int j = 0; j < 8; j++) { acc0[j] = bsv; acc1[j] = bsv; }
    #pragma unroll
    for (int dy = 0; dy < 4; dy++) {
        float tp[10];
        #pragma unroll
        for (int k = 0; k < 10; k++) tp[k] = pl[r0 + dy][c0 + k];
        if (dy < 3) {
            #pragma unroll
            for (int dx = 0; dx < 3; dx++)
                #pragma unroll
                for (int j = 0; j < 8; j++)
                    acc0[j] = fmaf(w9[dy * 3 + dx], tp[j + dx], acc0[j]);
        }
        if (dy >= 1) {
            #pragma unroll
            for (int dx = 0; dx < 3; dx++)
                #pragma unroll
                for (int j = 0; j < 8; j++)
                    acc1[j] = fmaf(w9[(dy - 1) * 3 + dx], tp[j + dx], acc1[j]);
        }
    }
    uint4 o0, o1;
    o0.x = (unsigned)f2bf(acc0[0]) | ((unsigned)f2bf(acc0[1]) << 16);
    o0.y = (unsigned)f2bf(acc0[2]) | ((unsigned)f2bf(acc0[3]) << 16);
    o0.z = (unsigned)f2bf(acc0[4]) | ((unsigned)f2bf(acc0[5]) << 16);
    o0.w = (unsigned)f2bf(acc0[6]) | ((unsigned)f2bf(acc0[7]) << 16);
    o1.x = (unsigned)f2bf(acc1[0]) | ((unsigned)f2bf(acc1[1]) << 16);
    o1.y = (unsigned)f2bf(acc1[2]) | ((unsigned)f2bf(acc1[3]) << 16);
    o1.z = (unsigned)f2bf(acc1[4]) | ((unsigned)f2bf(acc1[5]) << 16);
    o1.w = (unsigned)f2bf(acc1[6]) | ((unsigned)f2bf(acc1[7]) << 16);
    *(uint4*)(dst2 + ((r0 * 64 + c0) >> 1)) = o0;
    *(uint4*)(dst2 + (((r0 + 1) * 64 + c0) >> 1)) = o1;
}

// ---------------- fast gelu: A&S 7.1.25 3-term erf + hw rcp (max err ~2.5e-5) ---------
__device__ inline float gelu3(float x) {
    float z = x * 0.70710678118654752f;
    float a = fabsf(z);
    float t = __builtin_amdgcn_rcpf(fmaf(0.47047f, a, 1.0f));
    float p = t * (0.3480242f + t * (-0.0958798f + t * 0.7478556f));
    float e = __expf(-a * a);
    float r = 1.0f - p * e;                 // erf(|z|)
    float erfz = copysignf(r, z);
    return 0.5f * x * (1.0f + erfz);
}

// wave-shfl fp32 paired reduction + cross-wave LDS combine (2 barriers)
__device__ inline void wave_reduce2(float& a, float& b, float* sred, int t)
{
    #pragma unroll
    for (int off = 32; off; off >>= 1) { a += __shfl_xor(a, off); b += __shfl_xor(b, off); }
    int w = t >> 6, lane = t & 63;
    __syncthreads();
    if (lane == 0) { sred[w] = a; sred[4 + w] = b; }
    __syncthreads();
    a = sred[0] + sred[1] + sred[2] + sred[3];
    b = sred[4] + sred[5] + sred[6] + sred[7];
}

__device__ inline double block_reduce1(float s, double* red, int t)
{
    __syncthreads();
    red[t] = (double)s;
    __syncthreads();
    for (int st = 128; st; st >>= 1) {
        if (t < st) red[t] += red[t + st];
        __syncthreads();
    }
    return red[0];
}

// ---------------- fused FF on bf16 h; 2x8 stencil tile; shfl stats; cheap gelu --------
__global__ __launch_bounds__(256) void ff_fused_kernel(
    unsigned short* __restrict__ h, const float* __restrict__ w, const float* __restrict__ bias)
{
    __shared__ float pl[66][67];
    __shared__ float sred[8];
    int plane = blockIdx.x;
    int c = plane & (NFF - 1);
    const unsigned* h2 = (const unsigned*)(h + (size_t)plane * NP);
    unsigned* h2w = (unsigned*)(h + (size_t)plane * NP);
    int t = threadIdx.x;
    int rp = t >> 3, cg = t & 7;
    int r0 = rp * 2, c0 = cg * 8;
    if (t < 66) { pl[0][t] = 0.f; pl[65][t] = 0.f; }
    if (t >= 66 && t < 130) { int rr = t - 65; pl[rr][0] = 0.f; pl[rr][65] = 0.f; }

    uint4 u0 = *(const uint4*)(h2 + ((r0 * 64 + c0) >> 1));
    uint4 u1 = *(const uint4*)(h2 + (((r0 + 1) * 64 + c0) >> 1));
    float v[16]; float sf = 0.f, s2f = 0.f;
    {
        unsigned uu[8] = {u0.x, u0.y, u0.z, u0.w, u1.x, u1.y, u1.z, u1.w};
        #pragma unroll
        for (int i = 0; i < 8; i++) {
            float x0 = bf2f((unsigned short)(uu[i] & 0xffffu));
            float x1 = bf2f((unsigned short)(uu[i] >> 16));
            v[2 * i] = x0; v[2 * i + 1] = x1;
            sf += x0 + x1;
            s2f += x0 * x0 + x1 * x1;
        }
    }
    wave_reduce2(sf, s2f, sred, t);
    float mf = sf * (1.f / NP);
    float var = s2f * (1.f / NP) - mf * mf;
    float rs = rsqrtf(var + CEPS);

    float w9[9];
    #pragma unroll
    for (int k = 0; k < 9; k++) w9[k] = w[c * 9 + k];
    float bsv = bias[c];

    #pragma unroll
    for (int j = 0; j < 8; j++) {
        float gx = gelu3((v[j] - mf) * rs);
        v[j] = gx;
        pl[r0 + 1][c0 + 1 + j] = gx;
    }
    #pragma unroll
    for (int j = 0; j < 8; j++) {
        float gx = gelu3((v[8 + j] - mf) * rs);
        v[8 + j] = gx;
        pl[r0 + 2][c0 + 1 + j] = gx;
    }
    __syncthreads();

    float acc0[8], acc1[8];
    #pragma unroll
    for (int j = 0; j < 8; j++) { acc0[j] = bsv; acc1[j] = bsv; }
    #pragma unroll
    for (int dy = 0; dy < 4; dy++) {
        float tp[10];
        #pragma unroll
        for (int k = 0; k < 10; k++) tp[k] = pl[r0 + dy][c0 + k];
        if (dy < 3) {
            #pragma unroll
            for (int dx = 0; dx < 3; dx++)
                #pragma unroll
                for (int j = 0; j < 8; j++)
                    acc0[j] = fmaf(w9[dy * 3 + dx], tp[j + dx], acc0[j]);
        }
        if (dy >= 1) {
            #pragma unroll
            for (int dx = 0; dx < 3; dx++)
                #pragma unroll
                for (int j = 0; j < 8; j++)
                    acc1[j] = fmaf(w9[(dy - 1) * 3 + dx], tp[j + dx], acc1[j]);
        }
    }
    float sg = 0.f, s2g = 0.f;
    #pragma unroll
    for (int j = 0; j < 8; j++) {
        sg += acc0[j] + acc1[j];
        s2g += acc0[j] * acc0[j] + acc1[j] * acc1[j];
    }
    wave_reduce2(sg, s2g, sred, t);
    float mf2 = sg * (1.f / NP);
    float var2 = s2g * (1.f / NP) - mf2 * mf2;
    float rs2 = rsqrtf(var2 + CEPS);

    uint4 o0, o1;
    {
        float r00 = v[0] + gelu3((acc0[0] - mf2) * rs2);
        float r01 = v[1] + gelu3((acc0[1] - mf2) * rs2);
        float r02 = v[2] + gelu3((acc0[2] - mf2) * rs2);
        float r03 = v[3] + gelu3((acc0[3] - mf2) * rs2);
        float r04 = v[4] + gelu3((acc0[4] - mf2) * rs2);
        float r05 = v[5] + gelu3((acc0[5] - mf2) * rs2);
        float r06 = v[6] + gelu3((acc0[6] - mf2) * rs2);
        float r07 = v[7] + gelu3((acc0[7] - mf2) * rs2);
        o0.x = (unsigned)f2bf(r00) | ((unsigned)f2bf(r01) << 16);
        o0.y = (unsigned)f2bf(r02) | ((unsigned)f2bf(r03) << 16);
        o0.z = (unsigned)f2bf(r04) | ((unsigned)f2bf(r05) << 16);
        o0.w = (unsigned)f2bf(r06) | ((unsigned)f2bf(r07) << 16);
        float r10 = v[8]  + gelu3((acc1[0] - mf2) * rs2);
        float r11 = v[9]  + gelu3((acc1[1] - mf2) * rs2);
        float r12 = v[10] + gelu3((acc1[2] - mf2) * rs2);
        float r13 = v[11] + gelu3((acc1[3] - mf2) * rs2);
        float r14 = v[12] + gelu3((acc1[4] - mf2) * rs2);
        float r15 = v[13] + gelu3((acc1[5] - mf2) * rs2);
        float r16 = v[14] + gelu3((acc1[6] - mf2) * rs2);
        float r17 = v[15] + gelu3((acc1[7] - mf2) * rs2);
        o1.x = (unsigned)f2bf(r10) | ((unsigned)f2bf(r11) << 16);
        o1.y = (unsigned)f2bf(r12) | ((unsigned)f2bf(r13) << 16);
        o1.z = (unsigned)f2bf(r14) | ((unsigned)f2bf(r15) << 16);
        o1.w = (unsigned)f2bf(r16) | ((unsigned)f2bf(r17) << 16);
    }
    *(uint4*)(h2w + ((r0 * 64 + c0) >> 1)) = o0;
    *(uint4*)(h2w + (((r0 + 1) * 64 + c0) >> 1)) = o1;
}

// ---------------- final instance norm in place on d_out (2-pass centered, f64 tree) ---
__global__ __launch_bounds__(256) void in_final_kernel(float* __restrict__ y)
{
    __shared__ double red[256];
    size_t base = (size_t)blockIdx.x * NP;
    int t = threadIdx.x;
    float v[16]; float sf = 0.f;
    #pragma unroll
    for (int i = 0; i < 16; i++) { float x = y[base + t + i * 256]; v[i] = x; sf += x; }
    double S = block_reduce1(sf, red, t);
    float mf = (float)(S * (1.0 / NP));
    float s2f = 0.f;
    #pragma unroll
    for (int i = 0; i < 16; i++) { float d = v[i] - mf; v[i] = d; s2f += d * d; }
    double S2 = block_reduce1(s2f, red, t);
    float rs = (float)(1.0 / sqrt(S2 * (1.0 / NP) + (double)CEPS));
    #pragma unroll
    for (int i = 0; i < 16; i++)
        y[base + t + i * 256] = v[i] * rs;
}

extern "C" void kernel_launch(void* const* d_in, const int* in_sizes, int n_in,
                              void* d_out, int out_size, void* d_ws, size_t ws_size,
                              hipStream_t stream)
{
    const float* x      = (const float*)d_in[0];
    const float* g      = (const float*)d_in[1];
    const float* bc     = (const float*)d_in[2];
    const float* w_qkv  = (const float*)d_in[3];
    const float* w_out  = (const float*)d_in[4];
    const float* b_out  = (const float*)d_in[5];
    const float* w_dw   = (const float*)d_in[6];
    const float* b_dw   = (const float*)d_in[7];
    const float* w_comb = (const float*)d_in[8];
    const float* b_comb = (const float*)d_in[9];
    const float* w_ff1  = (const float*)d_in[10];
    const float* b_ff1  = (const float*)d_in[11];
    const float* w_ffdw = (const float*)d_in[12];
    const float* b_ffdw = (const float*)d_in[13];
    const float* w_ff2  = (const float*)d_in[14];
    const float* b_ff2  = (const float*)d_in[15];
    float* out = (float*)d_out;
    float* ws  = (float*)d_ws;

    const size_t S = (size_t)NB * NC * NP;   // 16,777,216 floats (64 MiB)
    float* qkv   = ws + S;
    unsigned short* h1u   = (unsigned short*)ws;
    unsigned short* ctxu  = (unsigned short*)(ws + 2097152);
    unsigned short* convu = (unsigned short*)(ws + S);
    unsigned short* Fbufu = (unsigned short*)out;
    float* qrow    = ws;                       // 262144
    float* kheight = qrow + 262144;            // 262144
    float* kselb   = kheight + 262144;         // 262144
    float* vselb   = kselb + 262144;           // ends at 1048576
    int*   hswsl   = (int*)(ws + 1048576);     // 2048 ints
    float* rs_a    = ws + 1052672;             // 65536
    float* mrs_a   = rs_a + 65536;             // 65536
    float* Aab     = mrs_a + 65536;            // 768
    float* Bab     = Aab + 768;                // 768
    unsigned* pw_qkv = (unsigned*)out;
    unsigned* pwF    = (unsigned*)ws;
    float*    bF     = ws + 131072;
    unsigned* pw_ff1 = (unsigned*)(ws + 2 * S);            // 262144 u32
    unsigned* pw_ff2 = (unsigned*)(ws + 2 * S) + 262144;   // 262144 u32

    size_t need = 4 * S * sizeof(float);
    if (ws_size < need) {
        float val = 1024.0f + (float)(ws_size >> 20);
        diag_fill<<<(out_size + 255) / 256, 256, 0, stream>>>(out, val, out_size);
        return;
    }

    // 0. prepack W_qkv*diag(g) for q,k rows; cln stats; fold constants
    pack_wg_kernel<<<512, 256, 0, stream>>>(w_qkv, g, pw_qkv, 512 * 256);
    cln_stats_kernel<<<1024, 256, 0, stream>>>(x, rs_a, mrs_a);
    ab_kernel<<<3, 256, 0, stream>>>(w_qkv, g, bc, Aab, Bab);
    // 2. q,k = fold( (W_qkv g) * x ) with fused l2norm + qrow/kheight  (O=512, lazy v)
    gemm_mfma<false, true, true, false, false><<<dim3(32, 4, NB), 512, 0, stream>>>(
        x, 256, 256, nullptr, 0, 256, (const float*)pw_qkv, nullptr, nullptr, qkv, 768, 512,
        rs_a, mrs_a, Aab, Bab, qrow, kheight);
    // 5. select: top-k + k gather + index export
    select_kernel<<<NBH, 64, 0, stream>>>(qkv, qrow, kheight, kselb, hswsl);
    // 5b. lazy v from x with cln fold
    vsel_kernel<<<dim3(4, NBH), 256, 0, stream>>>(x, w_qkv, g, hswsl, rs_a, mrs_a,
                                                  Aab, Bab, vselb);
    // 6. attention -> compact bf16 ctx
    attn_kernel<<<dim3(16, NBH), 256, 0, stream>>>(qkv, kselb, vselb, ctxu);
    // 7. fused comb weight -> packed; prepack ff1/ff2 weights into dead qkv tail
    fuse_comb_kernel<<<512, 256, 0, stream>>>(w_comb, w_out, b_out, b_comb, pwF, bF);
    pack_w_plain_kernel<<<1024, 256, 0, stream>>>(w_ff1, pw_ff1, 1024 * 256);
    pack_w_plain_kernel<<<1024, 256, 0, stream>>>(w_ff2, pw_ff2, 256 * 1024);
    // 8. conv branch -> compact bf16 (dead qkv space)
    dwconv_kernel<<<NB * NC, 256, 0, stream>>>(x, w_dw, b_dw, convu, NC);
    // 9. attn_out = W_fused * [ctx; conv] (bf16 B, 2-MFMA) + b_fused + x -> bf16 d_out
    gemm_mfma<false, true, false, true, true><<<dim3(32, 2, NB), 512, 0, stream>>>(
        (const float*)ctxu, 256, 256, (const float*)convu, 256, 512,
        (const float*)pwF, bF, x, (float*)Fbufu, 256, 256,
        nullptr, nullptr, nullptr, nullptr, nullptr, nullptr);
    // 10. h1 = (pw_ff1) * attn_out (bf16 B, 2-MFMA, packed A) + b_ff1 -> bf16 ws[0,2S)
    gemm_mfma<false, true, false, true, true><<<dim3(32, 8, NB), 512, 0, stream>>>(
        (const float*)Fbufu, 256, 256, nullptr, 0, 256, (const float*)pw_ff1, b_ff1, nullptr,
        (float*)h1u, 1024, 1024, nullptr, nullptr, nullptr, nullptr, nullptr, nullptr);
    // 11. fused FF on bf16 h1 (in place)
    ff_fused_kernel<<<NB * NFF, 256, 0, stream>>>(h1u, w_ffdw, b_ffdw);
    // 12. y = (pw_ff2) * h1 (bf16 B, 2-MFMA, packed A) + b_ff2 -> d_out fp32
    gemm_mfma<false, true, false, false, true><<<dim3(32, 2, NB), 512, 0, stream>>>(
        (const float*)h1u, 1024, 1024, nullptr, 0, 1024, (const float*)pw_ff2, b_ff2, nullptr,
        out, 256, 256, nullptr, nullptr, nullptr, nullptr, nullptr, nullptr);
    // 13. final instance norm
    in_final_kernel<<<NB * NC, 256, 0, stream>>>(out);
}